// Round 1
// baseline (137.486 us; speedup 1.0000x reference)
//
#include <hip/hip_runtime.h>

typedef unsigned short ushort_t;
typedef unsigned int   uint_t;

typedef __attribute__((ext_vector_type(8))) short  short8;   // 8 bf16 in 4 VGPRs
typedef __attribute__((ext_vector_type(4))) short  short4v;  // 4 bf16 (b64)
typedef __attribute__((ext_vector_type(4))) float  float4v;  // MFMA 16x16 acc

#define BB    8
#define CC    256
#define HH    64
#define WW2   64
#define NPIX  4096   // H*W
#define MPOS  1024   // (H/2)*(W/2)
#define ICH   64

__device__ __forceinline__ float bf2f(ushort_t u) {
  return __uint_as_float(((uint_t)u) << 16);
}
__device__ __forceinline__ ushort_t f2bf(float f) {
  uint_t i = __float_as_uint(f);
  uint_t r = (i + 0x7FFFu + ((i >> 16) & 1u)) >> 16;  // RNE
  return (ushort_t)r;
}
__device__ __forceinline__ ushort_t f2bf_rna(float f) {   // cheap round-half-away
  return (ushort_t)((__float_as_uint(f) + 0x8000u) >> 16);
}
__device__ __forceinline__ uint_t pack2(float a, float b) {
  return (uint_t)f2bf(a) | ((uint_t)f2bf(b) << 16);
}

// ---------------------------------------------------------------------------
// K0: weight prep into coalesced-fragment layouts (unchanged):
//   wA2 [32 kblk][192 o][8 k], Wbf2 [8 icblk][256 o][8 ic], biasAll [192] f32
// ---------------------------------------------------------------------------
__global__ __launch_bounds__(256) void prep_kernel(
    const float* __restrict__ theta_w, const float* __restrict__ phi_w,
    const float* __restrict__ g_w, const float* __restrict__ W_w,
    const float* __restrict__ theta_b, const float* __restrict__ phi_b,
    const float* __restrict__ g_b,
    ushort_t* __restrict__ wA2, ushort_t* __restrict__ Wbf2,
    float* __restrict__ biasAll) {
  int i = blockIdx.x * 256 + threadIdx.x;
  if (i < 49152) {         // theta|phi|g -> wA2
    float v = (i < 16384) ? theta_w[i]
            : (i < 32768) ? phi_w[i - 16384]
                          : g_w[i - 32768];
    int o = i >> 8, c = i & 255;
    wA2[(c >> 3) * 1536 + o * 8 + (c & 7)] = f2bf(v);
  } else if (i < 65536) {  // W_w -> Wbf2
    int j = i - 49152;
    int o = j >> 6, ic = j & 63;
    Wbf2[(ic >> 3) * 2048 + o * 8 + (ic & 7)] = f2bf(W_w[j]);
  } else if (i < 65600)    biasAll[i - 65536] = theta_b[i - 65536];
  else if (i < 65664)      biasAll[i - 65536] = phi_b[i - 65600];
  else if (i < 65728)      biasAll[i - 65536] = g_b[i - 65664];
}

// ---------------------------------------------------------------------------
// K1: q/k/v conv GEMM + 2x2 maxpool. OCCUPANCY 4 blocks/CU (16 waves/CU):
// grid 1024 = 8 b x 32 row-pairs x 4 col-quarters; tile = 32 pixels
// (rows {2rj,2rj+1} x cols [16cq,16cq+16)), K=256 resident in LDS (16KB).
// Same swizzled staging / fragment layouts as before, halved per-thread work.
// ---------------------------------------------------------------------------
__global__ __launch_bounds__(256, 4) void qkv_kernel(
    const float* __restrict__ x, const ushort_t* __restrict__ wA2,
    const float* __restrict__ biasAll,
    ushort_t* __restrict__ qbuf, ushort_t* __restrict__ kTbuf,
    ushort_t* __restrict__ vTbuf) {
  __shared__ __align__(16) ushort_t Bsu[32 * 256];
  uint4* Bs16 = (uint4*)Bsu;
  int tid = threadIdx.x;
  int wave = tid >> 6, lane = tid & 63;
  int quad = lane >> 4, col = lane & 15;
  int b = blockIdx.x >> 7, t = blockIdx.x & 127;
  int rj = t >> 2, cq = t & 3;

  // ---- stage x tile: thread covers pixel `pos` (0..31), channels [cg*32,+32)
  {
    int pos = tid & 31, cg = tid >> 5;
    int prow = pos >> 4, pcol = pos & 15;
    const float* xsrc = x + (size_t)b * (CC * NPIX) +
                        (size_t)(2 * rj + prow) * WW2 + cq * 16 + pcol;
#pragma unroll
    for (int g = 0; g < 4; ++g) {
      float v[8];
#pragma unroll
      for (int j = 0; j < 8; ++j)
        v[j] = xsrc[(size_t)(cg * 32 + g * 8 + j) * NPIX];
      uint4 w;
      w.x = pack2(v[0], v[1]);
      w.y = pack2(v[2], v[3]);
      w.z = pack2(v[4], v[5]);
      w.w = pack2(v[6], v[7]);
      int jb = cg * 4 + g;  // 16B-block index in K (0..31)
      Bs16[pos * 32 + (jb & ~7) + ((jb & 7) ^ (pos & 7))] = w;
    }
  }
  __syncthreads();

  float4v acc[3][2];
#pragma unroll
  for (int ot = 0; ot < 3; ++ot) {
    int ob = wave * 48 + ot * 16 + quad * 4;
    float4v bv;
#pragma unroll
    for (int r = 0; r < 4; ++r) bv[r] = biasAll[ob + r];
    acc[ot][0] = bv;
    acc[ot][1] = bv;
  }

  const uint4* wA16 = (const uint4*)wA2;
#pragma unroll
  for (int ks = 0; ks < 8; ++ks) {
    int kblk = ks * 4 + quad;               // 16B-block index in K (0..31)
    short8 aw[3];
#pragma unroll
    for (int ot = 0; ot < 3; ++ot) {
      uint4 a = wA16[kblk * 192 + wave * 48 + ot * 16 + col];
      aw[ot] = *(const short8*)&a;
    }
#pragma unroll
    for (int s = 0; s < 2; ++s) {
      int lp = s * 16 + col;
      uint4 braw = Bs16[lp * 32 + (kblk & ~7) + ((kblk & 7) ^ (lp & 7))];
      short8 bx = *(const short8*)&braw;
#pragma unroll
      for (int ot = 0; ot < 3; ++ot)
        acc[ot][s] = __builtin_amdgcn_mfma_f32_16x16x32_bf16(aw[ot], bx, acc[ot][s], 0, 0, 0);
    }
  }

  // epilogue: lane value (o = ob+quad*4+r; tile pixel p = s*16+col,
  // i.e. image row 2rj+s, col cq*16+col)
#pragma unroll
  for (int ot = 0; ot < 3; ++ot) {
    int ob = wave * 48 + ot * 16;
    if (ob < 64) {  // theta -> qbuf[b][n][o]
#pragma unroll
      for (int s = 0; s < 2; ++s) {
        int n = (2 * rj + s) * WW2 + cq * 16 + col;
        uint2 u;
        u.x = pack2(acc[ot][s][0], acc[ot][s][1]);
        u.y = pack2(acc[ot][s][2], acc[ot][s][3]);
        *(uint2*)&qbuf[((size_t)(b * NPIX + n)) * ICH + ob + quad * 4] = u;
      }
    } else if (ob < 128) {  // phi -> pool -> kTbuf[b][m][ic]
      float4v pm;
#pragma unroll
      for (int r = 0; r < 4; ++r) {
        float v = fmaxf(acc[ot][0][r], acc[ot][1][r]);   // row pair
        pm[r] = fmaxf(v, __shfl_xor(v, 1));              // col pair
      }
      if ((lane & 1) == 0) {
        int m = rj * 32 + cq * 8 + (col >> 1);
        uint2 u;
        u.x = pack2(pm[0], pm[1]);
        u.y = pack2(pm[2], pm[3]);
        *(uint2*)&kTbuf[((size_t)(b * MPOS + m)) * ICH + (ob - 64) + quad * 4] = u;
      }
    } else {  // g -> pool -> vTbuf[b][ic][m]
      float4v pm;
#pragma unroll
      for (int r = 0; r < 4; ++r) {
        float v = fmaxf(acc[ot][0][r], acc[ot][1][r]);
        pm[r] = fmaxf(v, __shfl_xor(v, 1));
      }
      if ((lane & 1) == 0) {
        int m = rj * 32 + cq * 8 + (col >> 1);
#pragma unroll
        for (int r = 0; r < 4; ++r)
          vTbuf[((size_t)(b * ICH + (ob - 128) + quad * 4 + r)) * MPOS + m] = f2bf(pm[r]);
      }
    }
  }
}

// ---------------------------------------------------------------------------
// K2: FUSED attention + output conv + residual. OCCUPANCY: 512-thread blocks
// (8 waves -> 16 waves/CU). The 8 waves split the m-dimension: half h
// (waves h*4..h*4+3) processes kt in [h*8, h*8+8) with private K/V/P LDS
// buffers, so the two halves run concurrently with the same total barrier
// count as before. Out-conv is linear in attended, so no O-merge is needed:
// only the softmax denominator l is exchanged via LDS, and the out-conv
// contracts over BOTH halves' normalized P buffers (A-frags from LDS,
// B = Wbf2 from L2). Residual float4 x-loads are hoisted above the MFMA
// cluster; s_setprio(1) wraps MFMA clusters (T5).
// LDS: K 2x8KB | V 2x8KB | P 2x9KB = 50KB -> 2 blocks/CU.
// ---------------------------------------------------------------------------
__global__ __launch_bounds__(512, 2) void attn_out_kernel(
    const ushort_t* __restrict__ qbuf, const ushort_t* __restrict__ kTbuf,
    const ushort_t* __restrict__ vTbuf, const ushort_t* __restrict__ Wbf2,
    const float* __restrict__ W_b, const float* __restrict__ x,
    float* __restrict__ out) {
  __shared__ __align__(16) ushort_t SH[25600];  // 51200 B
  int tid  = threadIdx.x;
  int wid  = tid >> 6, lane = tid & 63;
  int quad = lane >> 4, col = lane & 15;
  int wrow = wid & 3, whalf = wid >> 2;
  int b = blockIdx.x >> 6, qt = blockIdx.x & 63;
  int hid = tid & 255;                       // id within half (256 threads)

  ushort_t* Ksh = SH + whalf * 4096;         // [64][64] swizzled, per half
  ushort_t* Vsh = SH + 8192 + whalf * 4096;  // [64 ic][64 m] swizzled, per half
  ushort_t* Psh = SH + 16384 + whalf * 4608; // [64][72], per half

  // Q A-fragments straight from global (one-time; both halves same rows)
  const ushort_t* qrow = qbuf + ((size_t)(b * NPIX + qt * 64 + wrow * 16 + col)) * ICH;
  short8 aQ0 = *(const short8*)&qrow[quad * 8];
  short8 aQ1 = *(const short8*)&qrow[32 + quad * 8];

  int krow0 = hid >> 3,         kblk0 = hid & 7;
  int krow1 = (hid + 256) >> 3, kblk1 = hid & 7;
  int vic = hid >> 2, vseg = hid & 3;
  int ktbase = whalf * 8;

  const uint4* ksrc = (const uint4*)(kTbuf + (size_t)b * MPOS * ICH);
  const ushort_t* vbase = vTbuf + ((size_t)(b * ICH + vic)) * MPOS;

  {
    uint4 k0 = ksrc[ktbase * 512 + hid], k1 = ksrc[ktbase * 512 + 256 + hid];
    const uint4* vsrc = (const uint4*)(vbase + ktbase * 64 + vseg * 16);
    uint4 v0 = vsrc[0], v1 = vsrc[1];
    *(uint4*)&Ksh[krow0 * 64 + ((kblk0 ^ (krow0 & 7)) * 8)] = k0;
    *(uint4*)&Ksh[krow1 * 64 + ((kblk1 ^ (krow1 & 7)) * 8)] = k1;
    *(uint4*)&Vsh[vic * 64 + (((vseg * 2 + 0) ^ (vic & 7)) * 8)] = v0;
    *(uint4*)&Vsh[vic * 64 + (((vseg * 2 + 1) ^ (vic & 7)) * 8)] = v1;
  }
  __syncthreads();

  const float4v zero4 = {0.f, 0.f, 0.f, 0.f};
  float l_lane[4] = {0.f, 0.f, 0.f, 0.f};
  float4v o_acc[4];
#pragma unroll
  for (int t = 0; t < 4; ++t) o_acc[t] = zero4;

  for (int i = 0; i < 8; ++i) {
    uint4 nk0, nk1, nv0, nv1;
    if (i < 7) {
      int kt = ktbase + i + 1;
      nk0 = ksrc[kt * 512 + hid];
      nk1 = ksrc[kt * 512 + 256 + hid];
      const uint4* vsrc = (const uint4*)(vbase + kt * 64 + vseg * 16);
      nv0 = vsrc[0];
      nv1 = vsrc[1];
    }

    // S = Q . K^T
    float4v s_acc[4];
    __builtin_amdgcn_s_setprio(1);
#pragma unroll
    for (int t = 0; t < 4; ++t) {
      float4v s = zero4;
      short8 bk0 = *(const short8*)&Ksh[(t * 16 + col) * 64 + ((quad ^ (col & 7)) * 8)];
      s = __builtin_amdgcn_mfma_f32_16x16x32_bf16(aQ0, bk0, s, 0, 0, 0);
      short8 bk1 = *(const short8*)&Ksh[(t * 16 + col) * 64 + (((4 + quad) ^ (col & 7)) * 8)];
      s = __builtin_amdgcn_mfma_f32_16x16x32_bf16(aQ1, bk1, s, 0, 0, 0);
      s_acc[t] = s;
    }
    __builtin_amdgcn_s_setprio(0);

    // P = exp(S); per-lane l accumulation; wave-private Ps rows (own half)
#pragma unroll
    for (int r = 0; r < 4; ++r) {
      int prow = (wrow * 16 + quad * 4 + r) * 72;
#pragma unroll
      for (int t = 0; t < 4; ++t) {
        float pv = __expf(s_acc[t][r]);
        l_lane[r] += pv;
        Psh[prow + t * 16 + col] = f2bf_rna(pv);
      }
    }

    // O += P . V
    __builtin_amdgcn_s_setprio(1);
#pragma unroll
    for (int kk = 0; kk < 2; ++kk) {
      short8 ap = *(const short8*)&Psh[(wrow * 16 + col) * 72 + kk * 32 + quad * 8];
#pragma unroll
      for (int t = 0; t < 4; ++t) {
        short8 bv = *(const short8*)&Vsh[(t * 16 + col) * 64 + (((kk * 4 + quad) ^ (col & 7)) * 8)];
        o_acc[t] = __builtin_amdgcn_mfma_f32_16x16x32_bf16(ap, bv, o_acc[t], 0, 0, 0);
      }
    }
    __builtin_amdgcn_s_setprio(0);

    __syncthreads();              // all waves done reading iter i
    if (i < 7) {
      *(uint4*)&Ksh[krow0 * 64 + ((kblk0 ^ (krow0 & 7)) * 8)] = nk0;
      *(uint4*)&Ksh[krow1 * 64 + ((kblk1 ^ (krow1 & 7)) * 8)] = nk1;
      *(uint4*)&Vsh[vic * 64 + (((vseg * 2 + 0) ^ (vic & 7)) * 8)] = nv0;
      *(uint4*)&Vsh[vic * 64 + (((vseg * 2 + 1) ^ (vic & 7)) * 8)] = nv1;
    }
    __syncthreads();              // next tile visible
  }

  // ---- merge softmax denominator across halves (K region reused as f32 buf)
  float* lbuf = (float*)SH;
#pragma unroll
  for (int r = 0; r < 4; ++r) lbuf[tid * 4 + r] = l_lane[r];
  __syncthreads();
  float inv_l[4];
#pragma unroll
  for (int r = 0; r < 4; ++r) {
    float l = l_lane[r] + lbuf[(tid ^ 256) * 4 + r];
    l += __shfl_xor(l, 1);
    l += __shfl_xor(l, 2);
    l += __shfl_xor(l, 4);
    l += __shfl_xor(l, 8);
    inv_l[r] = 1.0f / l;
  }

  // normalize partial O, write attended rows (bf16) into own half's Ps rows.
  // Same-wave rows -> no barrier needed before our own writes; one barrier
  // after so BOTH halves' Ps are visible to the out-conv.
#pragma unroll
  for (int r = 0; r < 4; ++r) {
    int prow = (wrow * 16 + quad * 4 + r) * 72;
#pragma unroll
    for (int t = 0; t < 4; ++t)
      Psh[prow + t * 16 + col] = f2bf(o_acc[t][r] * inv_l[r]);
  }
  __syncthreads();

  // ---- fused output conv: D[m=p(16 per wave)][n=o(128 per half)] + residual
  float4v cacc[8];
#pragma unroll
  for (int ot = 0; ot < 8; ++ot) {
    float bv = W_b[whalf * 128 + ot * 16 + col];
    float4v bvec = {bv, bv, bv, bv};
    cacc[ot] = bvec;
  }

  int pbase = qt * 64 + wrow * 16 + quad * 4;
  float4 xv[8];                   // hoisted residual loads (hidden under MFMAs)
#pragma unroll
  for (int ot = 0; ot < 8; ++ot) {
    int o = whalf * 128 + ot * 16 + col;
    xv[ot] = *(const float4*)&x[((size_t)(b * CC + o)) * NPIX + pbase];
  }

  const uint4* W16 = (const uint4*)Wbf2;
  __builtin_amdgcn_s_setprio(1);
#pragma unroll
  for (int h = 0; h < 2; ++h) {
    const ushort_t* Ph = SH + 16384 + h * 4608;
#pragma unroll
    for (int ks = 0; ks < 2; ++ks) {
      short8 ap = *(const short8*)&Ph[(wrow * 16 + col) * 72 + ks * 32 + quad * 8];
#pragma unroll
      for (int ot = 0; ot < 8; ++ot) {
        uint4 wr = W16[(ks * 4 + quad) * 256 + whalf * 128 + ot * 16 + col];
        short8 wf = *(const short8*)&wr;
        cacc[ot] = __builtin_amdgcn_mfma_f32_16x16x32_bf16(ap, wf, cacc[ot], 0, 0, 0);
      }
    }
  }
  __builtin_amdgcn_s_setprio(0);

#pragma unroll
  for (int ot = 0; ot < 8; ++ot) {
    int o = whalf * 128 + ot * 16 + col;
    size_t idx = ((size_t)(b * CC + o)) * NPIX + pbase;
    float4 ov;
    ov.x = cacc[ot][0] + xv[ot].x;
    ov.y = cacc[ot][1] + xv[ot].y;
    ov.z = cacc[ot][2] + xv[ot].z;
    ov.w = cacc[ot][3] + xv[ot].w;
    *(float4*)&out[idx] = ov;
  }
}

// ---------------------------------------------------------------------------
extern "C" void kernel_launch(void* const* d_in, const int* in_sizes, int n_in,
                              void* d_out, int out_size, void* d_ws, size_t ws_size,
                              hipStream_t stream) {
  const float* x       = (const float*)d_in[0];
  const float* g_w     = (const float*)d_in[1];
  const float* g_b     = (const float*)d_in[2];
  const float* theta_w = (const float*)d_in[3];
  const float* theta_b = (const float*)d_in[4];
  const float* phi_w   = (const float*)d_in[5];
  const float* phi_b   = (const float*)d_in[6];
  const float* W_w     = (const float*)d_in[7];
  const float* W_b     = (const float*)d_in[8];
  (void)in_sizes; (void)n_in; (void)out_size; (void)ws_size;

  char* ws = (char*)d_ws;
  ushort_t* wA2     = (ushort_t*)(ws + 0);         // 96KB bf16 [32][192][8]
  ushort_t* Wbf2    = (ushort_t*)(ws + 98304);     // 32KB bf16 [8][256][8]
  float*    biasAll = (float*)(ws + 131072);       // 768B
  ushort_t* qbuf    = (ushort_t*)(ws + 262144);    // 4MB bf16 [8][4096][64]
  ushort_t* kTbuf   = (ushort_t*)(ws + 4456448);   // 1MB bf16 [8][1024][64]
  ushort_t* vTbuf   = (ushort_t*)(ws + 5505024);   // 1MB bf16 [8][64][1024]
  float* out = (float*)d_out;

  prep_kernel<<<257, 256, 0, stream>>>(theta_w, phi_w, g_w, W_w,
                                       theta_b, phi_b, g_b,
                                       wA2, Wbf2, biasAll);
  qkv_kernel<<<1024, 256, 0, stream>>>(x, wA2, biasAll, qbuf, kTbuf, vTbuf);
  attn_out_kernel<<<512, 512, 0, stream>>>(qbuf, kTbuf, vTbuf, Wbf2, W_b, x, out);
}